// Round 5
// baseline (236.660 us; speedup 1.0000x reference)
//
#include <hip/hip_runtime.h>
#include <math.h>

#define IMG_H 2048
#define IMG_W 2048
#define NB    8
#define BORDER 10
#define REP_THR 0.6f
#define RPT   16   // output rows per thread

// Streaming NMS: each thread owns a 16-row x 4-col strip. It walks 18 input
// rows once each (1.125x read amplification vs 1.5x for the 4-row version),
// keeping a rolling 3-row window of horizontal 3-maxima in registers.
// BORDER=10 > stencil radius, so border pixels are unconditionally 0 and
// interior loads are unguarded; the y-halo at image top/bottom is clamped
// (affected rows are border-masked anyway, the clamp only prevents OOB).
// Output is write-once -> non-temporal stores keep L2 for input-halo reuse.

typedef float vfloat4 __attribute__((ext_vector_type(4)));  // native vec for nt builtin

__device__ __forceinline__ void nt_store4(float* p, float a, float b, float c, float d) {
    vfloat4 v = {a, b, c, d};
    __builtin_nontemporal_store(v, (vfloat4*)p);
}

struct RowH { float4 v; float4 h; };

__device__ __forceinline__ RowH load_row(const float* __restrict__ row) {
    RowH r;
    r.v = *(const float4*)row;
    const float l = row[-1];
    const float q = row[4];
    r.h.x = fmaxf(l,     fmaxf(r.v.x, r.v.y));
    r.h.y = fmaxf(r.v.x, fmaxf(r.v.y, r.v.z));
    r.h.z = fmaxf(r.v.y, fmaxf(r.v.z, r.v.w));
    r.h.w = fmaxf(r.v.z, fmaxf(r.v.w, q));
    return r;
}

__global__ __launch_bounds__(256) void nms_kernel(const float* __restrict__ in,
                                                  float* __restrict__ out) {
    const int tid = blockIdx.x * blockDim.x + threadIdx.x;  // < 8*128*512 = 2^19
    const int gx = tid & 511;          // 4-col group
    const int s  = (tid >> 9) & 127;   // 16-row strip
    const int b  = tid >> 16;          // image

    const int x4 = gx << 2;            // 0..2044
    const int y0 = s * RPT;            // 0..2032

    const size_t img_off = (size_t)b * IMG_H * IMG_W;
    float* obase = out + img_off + (size_t)y0 * IMG_W + x4;

    // Edge column groups (cols 0-3 and 2044-2047) are fully inside the
    // column border: write zeros, no loads (also avoids x OOB).
    if (gx == 0 || gx == 511) {
#pragma unroll
        for (int j = 0; j < RPT; ++j)
            nt_store4(obase + (size_t)j * IMG_W, 0.f, 0.f, 0.f, 0.f);
        return;
    }

    const float* ibase = in + img_off + x4;

    // Column border mask (wave-uniform per gx)
    const bool bx0 = (x4 + 0 >= BORDER) && (x4 + 0 < IMG_W - BORDER);
    const bool bx1 = (x4 + 1 >= BORDER) && (x4 + 1 < IMG_W - BORDER);
    const bool bx2 = (x4 + 2 >= BORDER) && (x4 + 2 < IMG_W - BORDER);
    const bool bx3 = (x4 + 3 >= BORDER) && (x4 + 3 < IMG_W - BORDER);

    // Prime the rolling window: rows y0-1 (clamped) and y0.
    const int ym = (y0 == 0) ? 0 : (y0 - 1);
    RowH A = load_row(ibase + (size_t)ym * IMG_W);
    RowH B = load_row(ibase + (size_t)y0 * IMG_W);

#pragma unroll
    for (int j = 0; j < RPT; ++j) {
        int yn = y0 + j + 1;
        if (yn > IMG_H - 1) yn = IMG_H - 1;   // only strip 127; rows masked anyway
        const RowH C = load_row(ibase + (size_t)yn * IMG_W);

        float4 m;
        m.x = fmaxf(A.h.x, fmaxf(B.h.x, C.h.x));
        m.y = fmaxf(A.h.y, fmaxf(B.h.y, C.h.y));
        m.z = fmaxf(A.h.z, fmaxf(B.h.z, C.h.z));
        m.w = fmaxf(A.h.w, fmaxf(B.h.w, C.h.w));

        const int y = y0 + j;
        const bool rowok = (y >= BORDER) && (y < IMG_H - BORDER);

        const float r0 = (B.v.x == m.x && B.v.x >= REP_THR && bx0 && rowok) ? 1.f : 0.f;
        const float r1 = (B.v.y == m.y && B.v.y >= REP_THR && bx1 && rowok) ? 1.f : 0.f;
        const float r2 = (B.v.z == m.z && B.v.z >= REP_THR && bx2 && rowok) ? 1.f : 0.f;
        const float r3 = (B.v.w == m.w && B.v.w >= REP_THR && bx3 && rowok) ? 1.f : 0.f;

        nt_store4(obase + (size_t)j * IMG_W, r0, r1, r2, r3);

        A = B; B = C;
    }
}

extern "C" void kernel_launch(void* const* d_in, const int* in_sizes, int n_in,
                              void* d_out, int out_size, void* d_ws, size_t ws_size,
                              hipStream_t stream) {
    const float* in = (const float*)d_in[0];
    float* out = (float*)d_out;
    const int total_threads = NB * (IMG_H / RPT) * (IMG_W / 4);  // 2^19
    const int block = 256;
    const int grid = total_threads / block;                      // 2048
    nms_kernel<<<grid, block, 0, stream>>>(in, out);
}

// Round 6
// 234.066 us; speedup vs baseline: 1.0111x; 1.0111x over previous
//
#include <hip/hip_runtime.h>
#include <math.h>

#define IMG_H 2048
#define IMG_W 2048
#define NB    8
#define BORDER 10
#define REP_THR 0.6f

// 8-col x 4-row patch per thread. Per input row, FOUR aligned float4 loads
// (x8-4, x8, x8+4, x8+8) cover the 10-wide horizontal window with no scalar
// gathers; the halo float4s are the neighboring threads' center loads -> L1
// hits. All 24 row-loads are independent (no rolling window) so the compiler
// can keep many in flight (R5's rolling window collapsed MLP: VGPR=28, 2.4
// TB/s). Regular stores (R5's non-temporal stores were a suspect regression).
// BORDER=10 > stencil radius 1 -> border pixels unconditionally 0, interior
// loads unguarded.
__global__ __launch_bounds__(256) void nms_kernel(const float* __restrict__ in,
                                                  float* __restrict__ out) {
    const int tid = blockIdx.x * blockDim.x + threadIdx.x;  // < 8*512*256 = 2^20
    const int gx = tid & 255;          // 8-col group
    const int gy = (tid >> 8) & 511;   // 4-row strip
    const int b  = tid >> 17;          // image

    const int x8 = gx << 3;            // 0..2040
    const int y0 = gy << 2;            // 0..2044

    const size_t img_off = (size_t)b * IMG_H * IMG_W;
    float* obase = out + img_off + (size_t)y0 * IMG_W + x8;

    // Fully-border patches: gx 0/255 (cols 0-7 / 2040-2047), gy<=1 (rows 0-7),
    // gy>=510 (rows 2040-2047): all inside the zeroed frame.
    if (gx == 0 || gx == 255 || gy <= 1 || gy >= 510) {
        const float4 z = make_float4(0.f, 0.f, 0.f, 0.f);
#pragma unroll
        for (int j = 0; j < 4; ++j) {
            *(float4*)(obase + (size_t)j * IMG_W)     = z;
            *(float4*)(obase + (size_t)j * IMG_W + 4) = z;
        }
        return;
    }

    const float* ibase = in + img_off + (size_t)(y0 - 1) * IMG_W + x8;

    float h[6][8];   // horizontal 3-max of rows y0-1 .. y0+4, 8 columns
    float c[4][8];   // center values of rows y0 .. y0+3
#pragma unroll
    for (int r = 0; r < 6; ++r) {
        const float* row = ibase + (size_t)r * IMG_W;
        const float4 L = *(const float4*)(row - 4);
        const float4 M = *(const float4*)(row);
        const float4 N = *(const float4*)(row + 4);
        const float4 R = *(const float4*)(row + 8);

        h[r][0] = fmaxf(L.w, fmaxf(M.x, M.y));
        h[r][1] = fmaxf(M.x, fmaxf(M.y, M.z));
        h[r][2] = fmaxf(M.y, fmaxf(M.z, M.w));
        h[r][3] = fmaxf(M.z, fmaxf(M.w, N.x));
        h[r][4] = fmaxf(M.w, fmaxf(N.x, N.y));
        h[r][5] = fmaxf(N.x, fmaxf(N.y, N.z));
        h[r][6] = fmaxf(N.y, fmaxf(N.z, N.w));
        h[r][7] = fmaxf(N.z, fmaxf(N.w, R.x));

        if (r >= 1 && r <= 4) {
            c[r - 1][0] = M.x; c[r - 1][1] = M.y; c[r - 1][2] = M.z; c[r - 1][3] = M.w;
            c[r - 1][4] = N.x; c[r - 1][5] = N.y; c[r - 1][6] = N.z; c[r - 1][7] = N.w;
        }
    }

    // Column border mask (per-thread constant)
    bool bx[8];
#pragma unroll
    for (int p = 0; p < 8; ++p)
        bx[p] = (x8 + p >= BORDER) && (x8 + p < IMG_W - BORDER);

#pragma unroll
    for (int j = 0; j < 4; ++j) {
        const int y = y0 + j;
        const bool rowok = (y >= BORDER) && (y < IMG_H - BORDER);

        float r0[8];
#pragma unroll
        for (int p = 0; p < 8; ++p) {
            const float m = fmaxf(h[j][p], fmaxf(h[j + 1][p], h[j + 2][p]));
            r0[p] = (c[j][p] == m && c[j][p] >= REP_THR && bx[p] && rowok) ? 1.f : 0.f;
        }
        float4 lo = make_float4(r0[0], r0[1], r0[2], r0[3]);
        float4 hi = make_float4(r0[4], r0[5], r0[6], r0[7]);
        *(float4*)(obase + (size_t)j * IMG_W)     = lo;
        *(float4*)(obase + (size_t)j * IMG_W + 4) = hi;
    }
}

extern "C" void kernel_launch(void* const* d_in, const int* in_sizes, int n_in,
                              void* d_out, int out_size, void* d_ws, size_t ws_size,
                              hipStream_t stream) {
    const float* in = (const float*)d_in[0];
    float* out = (float*)d_out;
    const int total_threads = NB * (IMG_H / 4) * (IMG_W / 8);  // 2^20
    const int block = 256;
    const int grid = total_threads / block;                    // 4096
    nms_kernel<<<grid, block, 0, stream>>>(in, out);
}

// Round 7
// 232.941 us; speedup vs baseline: 1.0160x; 1.0048x over previous
//
#include <hip/hip_runtime.h>
#include <math.h>
#include <stdint.h>

#define IMG_H 2048
#define IMG_W 2048
#define NB    8
#define BORDER 10
#define REP_THR 0.6f
#define BAND   8                 // output rows per block
#define SROWS  (BAND + 2)        // staged input rows (80 KB dynamic LDS)
#define NBANDS (IMG_H / BAND)    // 256

// Async-staged NMS. R1/R2/R5/R6 all plateaued at 75-86 us with hbm=2.85 TB/s,
// VALUBusy 9%, VGPR=32: read-latency bound (compiler keeps ~2 loads in flight
// per wave). global_load_lds makes reads fire-and-forget into LDS (no VGPR
// round-trip, deep vmcnt queue), like the 6.35 TB/s fill's stores.
// Each block: stage 10 contiguous full-width rows (80 KB) via 80x 1KB
// global_load_lds_dwordx4, one barrier, compute 8 rows from LDS.
// BORDER=10 > stencil radius -> border rows/cols unconditionally zero.

typedef __attribute__((address_space(3))) uint32_t       lds_u32_t;
typedef const __attribute__((address_space(1))) uint32_t glob_u32_t;

__global__ __launch_bounds__(256, 2) void nms_kernel(const float* __restrict__ in,
                                                     float* __restrict__ out) {
    extern __shared__ float lds[];   // SROWS * IMG_W floats

    const int s = blockIdx.x & (NBANDS - 1);   // band index 0..255
    const int b = blockIdx.x >> 8;             // image index
    const int y0 = s * BAND;
    const size_t img_off = (size_t)b * IMG_H * IMG_W;
    const int t = threadIdx.x;

    float* oband = out + img_off + (size_t)y0 * IMG_W;

    // Bands fully inside the border frame (rows 0-7 / 2040-2047): zeros only.
    if (s == 0 || s == NBANDS - 1) {
        const float4 z = make_float4(0.f, 0.f, 0.f, 0.f);
#pragma unroll
        for (int k = 0; k < 16; ++k)
            *(float4*)(oband + (size_t)(k * 256 + t) * 4) = z;
        return;
    }

    // --- async stage rows y0-1 .. y0+8 (contiguous 80 KB) into LDS ---
    const float* region = in + img_off + (size_t)(y0 - 1) * IMG_W;
    const int wave = t >> 6;
    const int lane = t & 63;
#pragma unroll
    for (int i = 0; i < SROWS * IMG_W / 256 / 4; ++i) {   // 20 chunks per wave
        const int c = i * 4 + wave;                       // chunk of 256 floats
        glob_u32_t* g = (glob_u32_t*)(region + c * 256 + lane * 4);
        lds_u32_t*  l = (lds_u32_t*)(lds + c * 256 + lane * 4);
        __builtin_amdgcn_global_load_lds(g, l, 16, 0, 0);
    }
    __syncthreads();

    // --- compute: thread t owns 8 cols x 8 rows ---
    const int x8 = t << 3;   // 0..2040

    // Edge column groups (cols 0-7, 2040-2047): fully border -> zeros.
    if (t == 0 || t == 255) {
        const float4 z = make_float4(0.f, 0.f, 0.f, 0.f);
#pragma unroll
        for (int j = 0; j < BAND; ++j) {
            *(float4*)(oband + (size_t)j * IMG_W + x8)     = z;
            *(float4*)(oband + (size_t)j * IMG_W + x8 + 4) = z;
        }
        return;
    }

    float h[SROWS][8];   // horizontal 3-max per staged row
    float cv[BAND][8];   // center values of rows y0 .. y0+7
#pragma unroll
    for (int r = 0; r < SROWS; ++r) {
        const float* row = lds + r * IMG_W + x8;
        const float4 L = *(const float4*)(row - 4);
        const float4 M = *(const float4*)(row);
        const float4 N = *(const float4*)(row + 4);
        const float4 R = *(const float4*)(row + 8);

        h[r][0] = fmaxf(L.w, fmaxf(M.x, M.y));
        h[r][1] = fmaxf(M.x, fmaxf(M.y, M.z));
        h[r][2] = fmaxf(M.y, fmaxf(M.z, M.w));
        h[r][3] = fmaxf(M.z, fmaxf(M.w, N.x));
        h[r][4] = fmaxf(M.w, fmaxf(N.x, N.y));
        h[r][5] = fmaxf(N.x, fmaxf(N.y, N.z));
        h[r][6] = fmaxf(N.y, fmaxf(N.z, N.w));
        h[r][7] = fmaxf(N.z, fmaxf(N.w, R.x));

        if (r >= 1 && r <= BAND) {
            cv[r-1][0] = M.x; cv[r-1][1] = M.y; cv[r-1][2] = M.z; cv[r-1][3] = M.w;
            cv[r-1][4] = N.x; cv[r-1][5] = N.y; cv[r-1][6] = N.z; cv[r-1][7] = N.w;
        }
    }

    bool bx[8];
#pragma unroll
    for (int p = 0; p < 8; ++p)
        bx[p] = (x8 + p >= BORDER) && (x8 + p < IMG_W - BORDER);

#pragma unroll
    for (int j = 0; j < BAND; ++j) {
        const int y = y0 + j;
        const bool rowok = (y >= BORDER) && (y < IMG_H - BORDER);

        float r0[8];
#pragma unroll
        for (int p = 0; p < 8; ++p) {
            const float m = fmaxf(h[j][p], fmaxf(h[j + 1][p], h[j + 2][p]));
            r0[p] = (cv[j][p] == m && cv[j][p] >= REP_THR && bx[p] && rowok) ? 1.f : 0.f;
        }
        *(float4*)(oband + (size_t)j * IMG_W + x8)     = make_float4(r0[0], r0[1], r0[2], r0[3]);
        *(float4*)(oband + (size_t)j * IMG_W + x8 + 4) = make_float4(r0[4], r0[5], r0[6], r0[7]);
    }
}

extern "C" void kernel_launch(void* const* d_in, const int* in_sizes, int n_in,
                              void* d_out, int out_size, void* d_ws, size_t ws_size,
                              hipStream_t stream) {
    const float* in = (const float*)d_in[0];
    float* out = (float*)d_out;
    const int grid = NB * NBANDS;                       // 2048 blocks
    const size_t shmem = (size_t)SROWS * IMG_W * 4;     // 80 KB
    nms_kernel<<<grid, 256, shmem, stream>>>(in, out);
}

// Round 8
// 230.615 us; speedup vs baseline: 1.0262x; 1.0101x over previous
//
#include <hip/hip_runtime.h>
#include <math.h>

#define IMG_H 2048
#define IMG_W 2048
#define NB    8
#define BORDER 10
#define REP_THR 0.6f

// 4-col x 8-row patch per thread. Lane stride = 16 B = access size, so EVERY
// global instruction (loads and stores) is a contiguous 1 KB wave access --
// the same full-line pattern as the 6.35 TB/s fill. Horizontal halo comes
// from two shifted float4 loads (x4-4, x4+4), which are neighbors' center
// lines -> L1/L2 hits; no scalar gathers (R2's weakness). Vertical amp
// 10/8 = 1.25x. BORDER=10 > stencil radius -> border pixels unconditionally
// zero, interior loads unguarded (gy/gx edge groups excluded below never
// generate OOB addresses).
__global__ __launch_bounds__(256) void nms_kernel(const float* __restrict__ in,
                                                  float* __restrict__ out) {
    const int tid = blockIdx.x * blockDim.x + threadIdx.x;  // < 8*256*512 = 2^20
    const int gx = tid & 511;          // 4-col group (lane-consecutive)
    const int gy = (tid >> 9) & 255;   // 8-row strip
    const int b  = tid >> 17;          // image

    const int x4 = gx << 2;            // 0..2044
    const int y0 = gy << 3;            // 0..2040

    const size_t img_off = (size_t)b * IMG_H * IMG_W;
    float* obase = out + img_off + (size_t)y0 * IMG_W + x4;

    // Fully-border patches: gy==0 (rows 0-7), gy==255 (rows 2040-2047),
    // gx==0 (cols 0-3), gx==511 (cols 2044-2047).
    if (gy == 0 || gy == 255 || gx == 0 || gx == 511) {
        const float4 z = make_float4(0.f, 0.f, 0.f, 0.f);
#pragma unroll
        for (int j = 0; j < 8; ++j)
            *(float4*)(obase + (size_t)j * IMG_W) = z;
        return;
    }

    // Interior: rows y0-1 .. y0+8 (all in [7, 2040]), cols x4-4 .. x4+7.
    const float* ibase = in + img_off + (size_t)(y0 - 1) * IMG_W + x4;

    float4 h[10];   // horizontal 3-max of the 10 staged rows
    float4 cv[8];   // center values of rows y0 .. y0+7
#pragma unroll
    for (int r = 0; r < 10; ++r) {
        const float* row = ibase + (size_t)r * IMG_W;
        const float4 L = *(const float4*)(row - 4);   // contiguous 1 KB wave access
        const float4 M = *(const float4*)(row);       // contiguous 1 KB wave access
        const float4 N = *(const float4*)(row + 4);   // contiguous 1 KB wave access
        float4 hh;
        hh.x = fmaxf(L.w, fmaxf(M.x, M.y));
        hh.y = fmaxf(M.x, fmaxf(M.y, M.z));
        hh.z = fmaxf(M.y, fmaxf(M.z, M.w));
        hh.w = fmaxf(M.z, fmaxf(M.w, N.x));
        h[r] = hh;
        if (r >= 1 && r <= 8) cv[r - 1] = M;
    }

    // Column border mask (per-thread constant)
    const bool bx0 = (x4 + 0 >= BORDER) && (x4 + 0 < IMG_W - BORDER);
    const bool bx1 = (x4 + 1 >= BORDER) && (x4 + 1 < IMG_W - BORDER);
    const bool bx2 = (x4 + 2 >= BORDER) && (x4 + 2 < IMG_W - BORDER);
    const bool bx3 = (x4 + 3 >= BORDER) && (x4 + 3 < IMG_W - BORDER);

#pragma unroll
    for (int j = 0; j < 8; ++j) {
        const int y = y0 + j;
        const bool rowok = (y >= BORDER) && (y < IMG_H - BORDER);

        float4 m;
        m.x = fmaxf(h[j].x, fmaxf(h[j + 1].x, h[j + 2].x));
        m.y = fmaxf(h[j].y, fmaxf(h[j + 1].y, h[j + 2].y));
        m.z = fmaxf(h[j].z, fmaxf(h[j + 1].z, h[j + 2].z));
        m.w = fmaxf(h[j].w, fmaxf(h[j + 1].w, h[j + 2].w));

        float4 r;
        r.x = (cv[j].x == m.x && cv[j].x >= REP_THR && bx0 && rowok) ? 1.f : 0.f;
        r.y = (cv[j].y == m.y && cv[j].y >= REP_THR && bx1 && rowok) ? 1.f : 0.f;
        r.z = (cv[j].z == m.z && cv[j].z >= REP_THR && bx2 && rowok) ? 1.f : 0.f;
        r.w = (cv[j].w == m.w && cv[j].w >= REP_THR && bx3 && rowok) ? 1.f : 0.f;

        *(float4*)(obase + (size_t)j * IMG_W) = r;   // contiguous 1 KB wave store
    }
}

extern "C" void kernel_launch(void* const* d_in, const int* in_sizes, int n_in,
                              void* d_out, int out_size, void* d_ws, size_t ws_size,
                              hipStream_t stream) {
    const float* in = (const float*)d_in[0];
    float* out = (float*)d_out;
    const int total_threads = NB * (IMG_H / 8) * (IMG_W / 4);  // 2^20
    const int block = 256;
    const int grid = total_threads / block;                    // 4096
    nms_kernel<<<grid, block, 0, stream>>>(in, out);
}